// Round 13
// baseline (59.181 us; speedup 1.0000x reference)
//
#include <hip/hip_runtime.h>

// (min,+) DP, wave-specialized, TWO images per block, 4 waves, grid=256
// = 1 block/CU (grid-limited) so each wave owns a SIMD:
//   wave 0: chain image A   wave 1: chain image B   (uncontended SIMDs)
//   wave 2: prep image A    wave 3: prep image B    (8 rows/chunk each)
// R9 showed the chain runs 310 cyc/row at 1 block/CU vs 515 at 2 blocks/CU
// (issue-slot contention); this gets the fast regime in a single round.
// LDS: 2 img x 2 buf x 8 rows x 1KB = 32 KB.

#define HH 256
#define WW 256
#define CH 8           // rows per chunk
#define NCH 32         // chunks per image
#define NULLV 1e30f

#define SBAR() __builtin_amdgcn_sched_barrier(0)

template<int CTRL, int ROWM>
__device__ __forceinline__ float dpp_mov(float x, float oldv) {
    return __builtin_bit_cast(float, __builtin_amdgcn_update_dpp(
        __builtin_bit_cast(int, oldv), __builtin_bit_cast(int, x),
        CTRL, ROWM, 0xF, false));
}

__device__ __forceinline__ float wave_iscan_add(float x) {
    x += dpp_mov<0x111, 0xF>(x, 0.0f);  // row_shr:1
    x += dpp_mov<0x112, 0xF>(x, 0.0f);  // row_shr:2
    x += dpp_mov<0x114, 0xF>(x, 0.0f);  // row_shr:4
    x += dpp_mov<0x118, 0xF>(x, 0.0f);  // row_shr:8
    x += dpp_mov<0x142, 0xA>(x, 0.0f);  // row_bcast:15 -> rows 1,3
    x += dpp_mov<0x143, 0xC>(x, 0.0f);  // row_bcast:31 -> rows 2,3
    return x;
}

__device__ __forceinline__ float wave_iscan_min(float x) {
    x = fminf(x, dpp_mov<0x111, 0xF>(x, NULLV));
    x = fminf(x, dpp_mov<0x112, 0xF>(x, NULLV));
    x = fminf(x, dpp_mov<0x114, 0xF>(x, NULLV));
    x = fminf(x, dpp_mov<0x118, 0xF>(x, NULLV));
    x = fminf(x, dpp_mov<0x142, 0xA>(x, NULLV));
    x = fminf(x, dpp_mov<0x143, 0xC>(x, NULLV));
    return x;
}

__device__ __forceinline__ float softplus_f(float x) {
    float ax = fabsf(x);
    float t  = __expf(-ax);
    return fmaxf(x, 0.0f) + __logf(1.0f + t);
}

// full-row cumsum of softplus for one row; returns S at cols 4l..4l+3
__device__ __forceinline__ float4 prep_row(float4 c) {
    float t0 = softplus_f(c.x);
    float t1 = t0 + softplus_f(c.y);
    float t2 = t1 + softplus_f(c.z);
    float t3 = t2 + softplus_f(c.w);
    float s    = wave_iscan_add(t3);
    float soff = dpp_mov<0x138, 0xF>(s, 0.0f);  // wave_shr:1, lane0 -> 0
    return make_float4(soff + t0, soff + t1, soff + t2, soff + t3);
}

__global__ __launch_bounds__(256, 1) void dp_kernel(const float* __restrict__ img,
                                                    float* __restrict__ out) {
    const int tid = threadIdx.x;
    const int wid = tid >> 6;      // 0,1 = chain (img A,B); 2,3 = prep (img A,B)
    const int lane = tid & 63;

    // [image][buffer][row][col]  -> 32 KB
    __shared__ __align__(16) float sbuf[2][2][CH][WW];

    const int imgi = wid & 1;
    const float* gbase = img + (size_t)(2 * blockIdx.x + imgi) * HH * WW;

    if (wid < 2) {
        // ---------------- chain wave (own SIMD, uncontended) ----------------
        __builtin_amdgcn_s_setprio(1);
        float v0, v1, v2, v3;

        auto row_step = [&](const float4& S) {
            float soff = dpp_mov<0x138, 0xF>(S.w, 0.0f);  // S[4l-1]
            float vm1  = dpp_mov<0x138, 0xF>(v3, NULLV);  // v[4l-1]
            float B0 = fminf(v0, vm1) - soff;
            float B1 = fminf(v1, v0) - S.x;
            float B2 = fminf(v2, v1) - S.y;
            float B3 = fminf(v3, v2) - S.z;
            float m1 = fminf(B0, B1);
            float m2 = fminf(m1, B2);
            float m3 = fminf(m2, B3);
            float mm   = wave_iscan_min(m3);
            float moff = dpp_mov<0x138, 0xF>(mm, NULLV);
            v0 = S.x + fminf(moff, B0);
            v1 = S.y + fminf(moff, m1);
            v2 = S.z + fminf(moff, m2);
            v3 = S.w + fminf(moff, m3);
        };

#define RD(buf, i) (*reinterpret_cast<const float4*>(&(buf)[i][lane * 4]))

        // chunk 0 (peel row-0 init); whole chunk -> registers first
        __syncthreads();
        {
            const float(*buf)[WW] = sbuf[imgi][0];
            float4 R0 = RD(buf, 0), R1 = RD(buf, 1), R2 = RD(buf, 2),
                   R3 = RD(buf, 3), R4 = RD(buf, 4), R5 = RD(buf, 5),
                   R6 = RD(buf, 6), R7 = RD(buf, 7);
            v0 = R0.x; v1 = R0.y; v2 = R0.z; v3 = R0.w;
            row_step(R1); row_step(R2); row_step(R3); row_step(R4);
            row_step(R5); row_step(R6); row_step(R7);
        }
        // chunks 1..31
        for (int k = 1; k < NCH; ++k) {
            __syncthreads();
            const float(*buf)[WW] = sbuf[imgi][k & 1];
            float4 R0 = RD(buf, 0), R1 = RD(buf, 1), R2 = RD(buf, 2),
                   R3 = RD(buf, 3), R4 = RD(buf, 4), R5 = RD(buf, 5),
                   R6 = RD(buf, 6), R7 = RD(buf, 7);
            row_step(R0); row_step(R1); row_step(R2); row_step(R3);
            row_step(R4); row_step(R5); row_step(R6); row_step(R7);
        }
#undef RD
        if (lane == 63) out[2 * blockIdx.x + imgi] = v3;
    } else {
        // ---------------- prep wave: 8 rows/chunk for its image ----------------
        const float4* gp = reinterpret_cast<const float4*>(gbase) + lane;

        // preload chunk 0's rows (8 x 1KB in flight)
        float4 L0 = gp[(size_t)0 * 64], L1 = gp[(size_t)1 * 64];
        float4 L2 = gp[(size_t)2 * 64], L3 = gp[(size_t)3 * 64];
        float4 L4 = gp[(size_t)4 * 64], L5 = gp[(size_t)5 * 64];
        float4 L6 = gp[(size_t)6 * 64], L7 = gp[(size_t)7 * 64];
        SBAR();

        for (int k = 0; k < NCH; ++k) {
            // issue next chunk's loads BEFORE computing current (loop-carried;
            // cannot sink past the __syncthreads below)
            float4 N0 = L0, N1 = L1, N2 = L2, N3 = L3;
            float4 N4 = L4, N5 = L5, N6 = L6, N7 = L7;
            if (k + 1 < NCH) {
                const size_t rn = (size_t)(k + 1) * CH;
                N0 = gp[(rn + 0) * 64]; N1 = gp[(rn + 1) * 64];
                N2 = gp[(rn + 2) * 64]; N3 = gp[(rn + 3) * 64];
                N4 = gp[(rn + 4) * 64]; N5 = gp[(rn + 5) * 64];
                N6 = gp[(rn + 6) * 64]; N7 = gp[(rn + 7) * 64];
            }
            SBAR();
            float(*buf)[WW] = sbuf[imgi][k & 1];
            *reinterpret_cast<float4*>(&buf[0][lane * 4]) = prep_row(L0);
            *reinterpret_cast<float4*>(&buf[1][lane * 4]) = prep_row(L1);
            *reinterpret_cast<float4*>(&buf[2][lane * 4]) = prep_row(L2);
            *reinterpret_cast<float4*>(&buf[3][lane * 4]) = prep_row(L3);
            *reinterpret_cast<float4*>(&buf[4][lane * 4]) = prep_row(L4);
            *reinterpret_cast<float4*>(&buf[5][lane * 4]) = prep_row(L5);
            *reinterpret_cast<float4*>(&buf[6][lane * 4]) = prep_row(L6);
            *reinterpret_cast<float4*>(&buf[7][lane * 4]) = prep_row(L7);
            __syncthreads();                       // publish chunk k
            L0 = N0; L1 = N1; L2 = N2; L3 = N3;
            L4 = N4; L5 = N5; L6 = N6; L7 = N7;
        }
    }
}

extern "C" void kernel_launch(void* const* d_in, const int* in_sizes, int n_in,
                              void* d_out, int out_size, void* d_ws, size_t ws_size,
                              hipStream_t stream) {
    const float* img = (const float*)d_in[0];
    float* out = (float*)d_out;
    dp_kernel<<<out_size / 2, 256, 0, stream>>>(img, out);
}

// Round 14
// 45.191 us; speedup vs baseline: 1.3096x; 1.3096x over previous
//
#include <hip/hip_runtime.h>

// (min,+) DP, wave-specialized. 2 images/block, 8 waves, grid=256 (1/CU):
//   wave 0:  chain image A      wave 1:  chain image B
//   waves 2-7: prep (3 per image: rows 0-2 / 3-5 / 6-7 of each 8-row chunk)
// Balance (measured): chain ~310cyc/row when its SIMD has <=1 co-wave (R9);
// prep total ~141k cyc/image -> 3 waves => 47k << chain 79k. Chain-bound,
// single round. LDS: 2 img x 2 buf x 8 rows x 1KB = 32 KB.

#define HH 256
#define WW 256
#define CH 8           // rows per chunk
#define NCH 32         // chunks per image
#define NULLV 1e30f

#define SBAR() __builtin_amdgcn_sched_barrier(0)

template<int CTRL, int ROWM>
__device__ __forceinline__ float dpp_mov(float x, float oldv) {
    return __builtin_bit_cast(float, __builtin_amdgcn_update_dpp(
        __builtin_bit_cast(int, oldv), __builtin_bit_cast(int, x),
        CTRL, ROWM, 0xF, false));
}

__device__ __forceinline__ float wave_iscan_add(float x) {
    x += dpp_mov<0x111, 0xF>(x, 0.0f);  // row_shr:1
    x += dpp_mov<0x112, 0xF>(x, 0.0f);  // row_shr:2
    x += dpp_mov<0x114, 0xF>(x, 0.0f);  // row_shr:4
    x += dpp_mov<0x118, 0xF>(x, 0.0f);  // row_shr:8
    x += dpp_mov<0x142, 0xA>(x, 0.0f);  // row_bcast:15 -> rows 1,3
    x += dpp_mov<0x143, 0xC>(x, 0.0f);  // row_bcast:31 -> rows 2,3
    return x;
}

__device__ __forceinline__ float wave_iscan_min(float x) {
    x = fminf(x, dpp_mov<0x111, 0xF>(x, NULLV));
    x = fminf(x, dpp_mov<0x112, 0xF>(x, NULLV));
    x = fminf(x, dpp_mov<0x114, 0xF>(x, NULLV));
    x = fminf(x, dpp_mov<0x118, 0xF>(x, NULLV));
    x = fminf(x, dpp_mov<0x142, 0xA>(x, NULLV));
    x = fminf(x, dpp_mov<0x143, 0xC>(x, NULLV));
    return x;
}

__device__ __forceinline__ float softplus_f(float x) {
    float ax = fabsf(x);
    float t  = __expf(-ax);
    return fmaxf(x, 0.0f) + __logf(1.0f + t);
}

// full-row cumsum of softplus for one row; returns S at cols 4l..4l+3
__device__ __forceinline__ float4 prep_row(float4 c) {
    float t0 = softplus_f(c.x);
    float t1 = t0 + softplus_f(c.y);
    float t2 = t1 + softplus_f(c.z);
    float t3 = t2 + softplus_f(c.w);
    float s    = wave_iscan_add(t3);
    float soff = dpp_mov<0x138, 0xF>(s, 0.0f);  // wave_shr:1, lane0 -> 0
    return make_float4(soff + t0, soff + t1, soff + t2, soff + t3);
}

// prep worker: NR rows (at chunk-offset row0) of every chunk; loop-carried
// next-chunk loads so HBM latency hides under compute + barrier wait.
template<int NR>
__device__ __forceinline__ void prep_run(const float4* gp, int row0,
                                         float* b0, float* b1, int lane) {
    float4 L0, L1, L2;
    L0 = gp[(size_t)(row0 + 0) * 64];
    if constexpr (NR > 1) L1 = gp[(size_t)(row0 + 1) * 64];
    if constexpr (NR > 2) L2 = gp[(size_t)(row0 + 2) * 64];
    SBAR();
    for (int k = 0; k < NCH; ++k) {
        float4 N0 = L0, N1 = L1, N2 = L2;
        if (k + 1 < NCH) {
            const size_t rn = (size_t)(k + 1) * CH + row0;
            N0 = gp[(rn + 0) * 64];
            if constexpr (NR > 1) N1 = gp[(rn + 1) * 64];
            if constexpr (NR > 2) N2 = gp[(rn + 2) * 64];
        }
        SBAR();
        float* buf = (k & 1) ? b1 : b0;
        *reinterpret_cast<float4*>(&buf[0 * WW + lane * 4]) = prep_row(L0);
        if constexpr (NR > 1)
            *reinterpret_cast<float4*>(&buf[1 * WW + lane * 4]) = prep_row(L1);
        if constexpr (NR > 2)
            *reinterpret_cast<float4*>(&buf[2 * WW + lane * 4]) = prep_row(L2);
        __syncthreads();                       // publish chunk k
        L0 = N0; L1 = N1; L2 = N2;
    }
}

__global__ __launch_bounds__(512, 1) void dp_kernel(const float* __restrict__ img,
                                                    float* __restrict__ out) {
    const int tid = threadIdx.x;
    const int wid = tid >> 6;
    const int lane = tid & 63;

    // [image][buffer][row][col] -> 32 KB
    __shared__ __align__(16) float sbuf[2][2][CH][WW];

    if (wid < 2) {
        // ---------------- chain waves (one per image) ----------------
        const int imgi = wid;
        __builtin_amdgcn_s_setprio(1);
        float v0, v1, v2, v3;

        auto row_step = [&](const float4& S) {
            float soff = dpp_mov<0x138, 0xF>(S.w, 0.0f);  // S[4l-1]
            float vm1  = dpp_mov<0x138, 0xF>(v3, NULLV);  // v[4l-1]
            float B0 = fminf(v0, vm1) - soff;
            float B1 = fminf(v1, v0) - S.x;
            float B2 = fminf(v2, v1) - S.y;
            float B3 = fminf(v3, v2) - S.z;
            float m1 = fminf(B0, B1);
            float m2 = fminf(m1, B2);
            float m3 = fminf(m2, B3);
            float mm   = wave_iscan_min(m3);
            float moff = dpp_mov<0x138, 0xF>(mm, NULLV);
            v0 = S.x + fminf(moff, B0);
            v1 = S.y + fminf(moff, m1);
            v2 = S.z + fminf(moff, m2);
            v3 = S.w + fminf(moff, m3);
        };

#define RD(buf, i) (*reinterpret_cast<const float4*>(&(buf)[i][lane * 4]))
        // chunk 0 (peel row-0 init); whole chunk -> registers first
        __syncthreads();
        {
            const float(*buf)[WW] = sbuf[imgi][0];
            float4 R0 = RD(buf, 0), R1 = RD(buf, 1), R2 = RD(buf, 2),
                   R3 = RD(buf, 3), R4 = RD(buf, 4), R5 = RD(buf, 5),
                   R6 = RD(buf, 6), R7 = RD(buf, 7);
            v0 = R0.x; v1 = R0.y; v2 = R0.z; v3 = R0.w;
            row_step(R1); row_step(R2); row_step(R3); row_step(R4);
            row_step(R5); row_step(R6); row_step(R7);
        }
        for (int k = 1; k < NCH; ++k) {
            __syncthreads();
            const float(*buf)[WW] = sbuf[imgi][k & 1];
            float4 R0 = RD(buf, 0), R1 = RD(buf, 1), R2 = RD(buf, 2),
                   R3 = RD(buf, 3), R4 = RD(buf, 4), R5 = RD(buf, 5),
                   R6 = RD(buf, 6), R7 = RD(buf, 7);
            row_step(R0); row_step(R1); row_step(R2); row_step(R3);
            row_step(R4); row_step(R5); row_step(R6); row_step(R7);
        }
#undef RD
        if (lane == 63) out[2 * blockIdx.x + imgi] = v3;
    } else {
        // ---------------- prep waves: 3 per image ----------------
        const int imgi = (wid - 2) & 1;        // waves 2,4,6 -> A; 3,5,7 -> B
        const int pw   = (wid - 2) >> 1;       // 0,1,2
        const float* gbase = img + (size_t)(2 * blockIdx.x + imgi) * HH * WW;
        const float4* gp = reinterpret_cast<const float4*>(gbase) + lane;
        const int row0 = pw * 3;               // 0,3,6
        float* b0 = &sbuf[imgi][0][row0][0];
        float* b1 = &sbuf[imgi][1][row0][0];
        if (pw < 2) prep_run<3>(gp, row0, b0, b1, lane);  // rows 0-2 / 3-5
        else        prep_run<2>(gp, row0, b0, b1, lane);  // rows 6-7
    }
}

extern "C" void kernel_launch(void* const* d_in, const int* in_sizes, int n_in,
                              void* d_out, int out_size, void* d_ws, size_t ws_size,
                              hipStream_t stream) {
    const float* img = (const float*)d_in[0];
    float* out = (float*)d_out;
    dp_kernel<<<out_size / 2, 512, 0, stream>>>(img, out);
}